// Round 2
// baseline (427.031 us; speedup 1.0000x reference)
//
#include <hip/hip_runtime.h>
#include <hip/hip_fp16.h>
#include <math.h>

#define NATOM 8192  // NB * NLOC

namespace {

typedef _Float16 half8 __attribute__((ext_vector_type(8)));
typedef _Float16 half2t __attribute__((ext_vector_type(2)));
typedef float f32x4 __attribute__((ext_vector_type(4)));

// ws layout (halfs): [0,32768) wkvp | [32768,49152) Wqp_t | [49152,65536) Whp_t
// wkvp: 32 MFMA A-tiles of 16 kv-columns each.
//   Tiles 0..15  = K columns (orig Wkv col c = d*8 + h)
//   Tiles 16..31 = V columns (orig Wkv col c = d*8 + 4 + h)
//   Tile T, row m (0..15): d = (T&15)*4 + (m>>2), h = m&3
//   A-frag element: lane l = lqk*16 + m holds features i = ks*32 + lqk*8 + jj
__global__ void pack_weights(const float* __restrict__ Wkv,
                             const float* __restrict__ Wq,
                             const float* __restrict__ Wh,
                             _Float16* __restrict__ out) {
  int tid = blockIdx.x * 256 + threadIdx.x;  // 0..65535
  if (tid < 32768) {
    // (i,c) with c fastest -> coalesced read of Wkv[i][c]
    int i = tid >> 9, c = tid & 511;
    int ks = i >> 5, jj = i & 7, lqk = (i >> 3) & 3;
    int d = c >> 3, e = c & 7, isv = e >> 2, h = e & 3;
    int T = isv * 16 + (d >> 2);
    int m = ((d & 3) << 2) | h;
    int l = lqk * 16 + m;
    out[(((T * 2 + ks) * 64) + l) * 8 + jj] = (_Float16)Wkv[i * 512 + c];
  } else if (tid < 49152) {
    int idx = tid - 32768;          // Wq is [i][c], 64x256
    int i = idx >> 8, c = idx & 255;
    out[32768 + c * 64 + i] = (_Float16)Wq[i * 256 + c];   // Wqp_t[c][i]
  } else {
    int idx = tid - 49152;          // Wh is [k][c], 256x64
    int k = idx >> 6, c = idx & 63;
    out[49152 + c * 256 + k] = (_Float16)Wh[k * 64 + c];   // Whp_t[c][k]
  }
}

__device__ __forceinline__ float dot8(half8 a, half8 b, float acc) {
  acc = __builtin_amdgcn_fdot2((half2t){a[0], a[1]}, (half2t){b[0], b[1]}, acc, false);
  acc = __builtin_amdgcn_fdot2((half2t){a[2], a[3]}, (half2t){b[2], b[3]}, acc, false);
  acc = __builtin_amdgcn_fdot2((half2t){a[4], a[5]}, (half2t){b[4], b[5]}, acc, false);
  acc = __builtin_amdgcn_fdot2((half2t){a[6], a[7]}, (half2t){b[6], b[7]}, acc, false);
  return acc;
}

__global__ __launch_bounds__(256, 8)
void local_atten_kernel(const float* __restrict__ g1,
                        const float* __restrict__ gg1,
                        const int* __restrict__ mask,
                        const _Float16* __restrict__ wpack,
                        const float* __restrict__ bh,
                        float* __restrict__ out) {
  // LDS: 8192 + 128 + 3072 + 512 + 512 = 12416 B. With VGPR<=64 (forced by
  // launch_bounds) this gives 8 blocks/CU = 32 waves/CU, 2x the old occupancy.
  __shared__ __align__(16) __half gs[64 * 64];          // gg1 tile, fp16, swizzled
  __shared__ __align__(16) __half g1h[64];
  __shared__ __align__(16) unsigned char blob[3072];    // qs+sred ; later redbuf
  __shared__ __align__(8) __half aws2[64][4];           // softmax weights [j][h]
  __shared__ __align__(16) __half rets[256];            // o flat k = h*64 + d

  float* qs = reinterpret_cast<float*>(blob);                    // [256] fp32
  __half (*sred)[4][64] = reinterpret_cast<__half(*)[4][64]>(blob + 1024);  // [w][h][j]
  float (*redbuf)[64] = reinterpret_cast<float(*)[64]>(blob);    // [w][c] (aliases qs)

  const _Float16* wkvp = wpack;
  const _Float16* wqp  = wpack + 32768;
  const _Float16* whp  = wpack + 49152;

  const int t = threadIdx.x;
  const int lane = t & 63;
  const int wave = t >> 6;
  const int lq = lane >> 4;   // quad within wave
  const int lr = lane & 15;
  const int atom = blockIdx.x;

  // ---- hoisted small loads: latency hidden behind staging + first barrier ----
  const int mreg = mask[(size_t)atom * 64 + lane];
  const float bhv = bh[lane];
  if (t < 64) g1h[t] = __float2half(g1[(size_t)atom * 64 + t]);

  // ---- stage gg1 tile (64 nei x 64 feat) as fp16, swizzled for B-frag b128 ----
  // logical gs[j][i]; physical half offset = j*64 + ((g ^ (j&7))<<3) + (i&7), g=i>>3
  {
    const float4* src = reinterpret_cast<const float4*>(gg1 + (size_t)atom * 4096);
#pragma unroll
    for (int r = 0; r < 4; ++r) {
      int idx4 = t + 256 * r;          // 0..1023 float4s
      int j = idx4 >> 4;               // neighbor row
      int i4 = (idx4 & 15) << 2;       // feature start (multiple of 4)
      float4 v = src[idx4];
      __half2 h01 = __floats2half2_rn(v.x, v.y);
      __half2 h23 = __floats2half2_rn(v.z, v.w);
      int g = i4 >> 3;
      int addr = j * 64 + ((g ^ (j & 7)) << 3) + (i4 & 7);
      union { __half2 h[2]; uint2 u; } pk;
      pk.h[0] = h01; pk.h[1] = h23;
      *reinterpret_cast<uint2*>(&gs[addr]) = pk.u;
    }
  }

  // B-fragment lane pointers: j = jt*16+lr, k-chunk g = ks*4+lq.
  // Swizzle term depends only on (lr,lq,ks): addr = jt*1024 + lr*64 + ((g^(lr&7))<<3)
  // -> two base pointers + jt*2048B immediate offsets; gs stays live all kernel
  // (no vbuf overwrite), so fragments are re-read per phase instead of pinned
  // in 32 VGPRs. ds_read_b128, uniform 8 accesses/bank (conflict-free).
  const __half* bp0 = &gs[lr * 64 + ((lq ^ (lr & 7)) << 3)];
  const __half* bp1 = &gs[lr * 64 + (((4 + lq) ^ (lr & 7)) << 3)];

  // ---- q = g1row @ Wq (fp16 dot2): thread t owns flat column t (= d*4 + h) ----
  __syncthreads();
  {
    float qacc = 0.f;
    const half8* wrow = reinterpret_cast<const half8*>(wqp + t * 64);
    const half8* grow = reinterpret_cast<const half8*>(&g1h[0]);
#pragma unroll
    for (int ks = 0; ks < 8; ++ks) qacc = dot8(wrow[ks], grow[ks], qacc);
    qs[t] = qacc;
  }
  __syncthreads();

  const half8* ap_base = reinterpret_cast<const half8*>(wkvp);

  // ---- phase 1: K-tiles only (T = wave*4 + it). Lane holds K[d=T*4+lq][h=r][j].
  // Score partial s[h][j] accumulates q[d][h]*K immediately; fold over lq after.
  float sacc[4][4];  // [jt][h]
#pragma unroll
  for (int jt = 0; jt < 4; ++jt)
#pragma unroll
    for (int h = 0; h < 4; ++h) sacc[jt][h] = 0.f;

#pragma unroll
  for (int it = 0; it < 4; ++it) {
    const int T = wave * 4 + it;
    half8 a0 = ap_base[T * 128 + lane];
    half8 a1 = ap_base[T * 128 + 64 + lane];
    const int d = T * 4 + lq;
    float4 q4 = *reinterpret_cast<const float4*>(&qs[d * 4]);  // q[d][0..3]
#pragma unroll
    for (int jt = 0; jt < 4; ++jt) {
      half8 b0 = *reinterpret_cast<const half8*>(bp0 + jt * 1024);
      half8 b1 = *reinterpret_cast<const half8*>(bp1 + jt * 1024);
      f32x4 acc = {0.f, 0.f, 0.f, 0.f};
      acc = __builtin_amdgcn_mfma_f32_16x16x32_f16(a0, b0, acc, 0, 0, 0);
      acc = __builtin_amdgcn_mfma_f32_16x16x32_f16(a1, b1, acc, 0, 0, 0);
      sacc[jt][0] = fmaf(acc[0], q4.x, sacc[jt][0]);
      sacc[jt][1] = fmaf(acc[1], q4.y, sacc[jt][1]);
      sacc[jt][2] = fmaf(acc[2], q4.z, sacc[jt][2]);
      sacc[jt][3] = fmaf(acc[3], q4.w, sacc[jt][3]);
    }
  }

  // fold score partials over all 4 quads (d-sum), publish per-wave partials
#pragma unroll
  for (int jt = 0; jt < 4; ++jt)
#pragma unroll
    for (int h = 0; h < 4; ++h) {
      sacc[jt][h] += __shfl_xor(sacc[jt][h], 16);
      sacc[jt][h] += __shfl_xor(sacc[jt][h], 32);
    }
  if (lq == 0) {
#pragma unroll
    for (int h = 0; h < 4; ++h)
#pragma unroll
      for (int jt = 0; jt < 4; ++jt)
        sred[wave][h][jt * 16 + lr] = __float2half(sacc[jt][h]);
  }
  __syncthreads();

  // ---- masked softmax over j (wave-wide): h = wave, j = lane ----
  {
    float s = __half2float(sred[0][wave][lane]) + __half2float(sred[1][wave][lane]) +
              __half2float(sred[2][wave][lane]) + __half2float(sred[3][wave][lane]);
    s *= 0.125f;                                          // 1/sqrt(64)
    s = mreg ? s : -INFINITY;
    float mx = s;
#pragma unroll
    for (int off = 32; off > 0; off >>= 1) mx = fmaxf(mx, __shfl_xor(mx, off));
    float pe = mreg ? __expf(s - mx) : 0.f;
    float sum = pe;
#pragma unroll
    for (int off = 32; off > 0; off >>= 1) sum += __shfl_xor(sum, off);
    float aw = (sum > 0.f) ? (pe / sum) : 0.f;
    aws2[lane][wave] = __float2half(aw);                  // [j][h]
  }
  __syncthreads();

  // ---- attnw for this lane's j-columns, as floats: awf[jt][h] = aw[h][jt*16+lr] ----
  float awf[4][4];
#pragma unroll
  for (int jt = 0; jt < 4; ++jt) {
    union { uint2 u; __half2 h[2]; } awu;
    awu.u = *reinterpret_cast<const uint2*>(&aws2[jt * 16 + lr][0]);  // b64 broadcast
    float2 f01 = __half22float2(awu.h[0]);
    float2 f23 = __half22float2(awu.h[1]);
    awf[jt][0] = f01.x; awf[jt][1] = f01.y; awf[jt][2] = f23.x; awf[jt][3] = f23.y;
  }

  // ---- phase 2: V-tiles (T = 16 + wave*4 + it). Lane holds V[d'=...][h=r][j];
  // PV contraction straight out of the accumulators: part[r] = sum_j aw[r][j]*V,
  // j-sum completed by a 16-lane butterfly. v never touches LDS.
#pragma unroll
  for (int it = 0; it < 4; ++it) {
    const int T = 16 + wave * 4 + it;
    half8 a0 = ap_base[T * 128 + lane];
    half8 a1 = ap_base[T * 128 + 64 + lane];
    float part[4] = {0.f, 0.f, 0.f, 0.f};
#pragma unroll
    for (int jt = 0; jt < 4; ++jt) {
      half8 b0 = *reinterpret_cast<const half8*>(bp0 + jt * 1024);
      half8 b1 = *reinterpret_cast<const half8*>(bp1 + jt * 1024);
      f32x4 acc = {0.f, 0.f, 0.f, 0.f};
      acc = __builtin_amdgcn_mfma_f32_16x16x32_f16(a0, b0, acc, 0, 0, 0);
      acc = __builtin_amdgcn_mfma_f32_16x16x32_f16(a1, b1, acc, 0, 0, 0);
      part[0] = fmaf(acc[0], awf[jt][0], part[0]);
      part[1] = fmaf(acc[1], awf[jt][1], part[1]);
      part[2] = fmaf(acc[2], awf[jt][2], part[2]);
      part[3] = fmaf(acc[3], awf[jt][3], part[3]);
    }
#pragma unroll
    for (int r = 0; r < 4; ++r) {
      part[r] += __shfl_xor(part[r], 1);
      part[r] += __shfl_xor(part[r], 2);
      part[r] += __shfl_xor(part[r], 4);
      part[r] += __shfl_xor(part[r], 8);
    }
    if (lr == 0) {
      const int d = (T - 16) * 4 + lq;      // covers 0..63 across waves*its*quads
#pragma unroll
      for (int r = 0; r < 4; ++r) rets[r * 64 + d] = __float2half(part[r]);
    }
  }
  __syncthreads();   // rets is cross-wave

  // ---- out = ret @ Wh + bh (fp16 dot2): c = lane, k-range = wave*64.. ----
  // Wh read straight from L2-hot wpack; 8-block TLP hides the latency.
  {
    float part = 0.f;
    const half8* wrow = reinterpret_cast<const half8*>(whp + lane * 256 + wave * 64);
    const half8* rrow = reinterpret_cast<const half8*>(&rets[wave * 64]);  // broadcast
#pragma unroll
    for (int ks = 0; ks < 8; ++ks) part = dot8(wrow[ks], rrow[ks], part);
    redbuf[wave][lane] = part;
  }
  __syncthreads();
  if (t < 64)
    out[(size_t)atom * 64 + t] =
        redbuf[0][t] + redbuf[1][t] + redbuf[2][t] + redbuf[3][t] + bhv;
}

}  // namespace

extern "C" void kernel_launch(void* const* d_in, const int* in_sizes, int n_in,
                              void* d_out, int out_size, void* d_ws, size_t ws_size,
                              hipStream_t stream) {
  const float* g1   = (const float*)d_in[0];
  const float* gg1  = (const float*)d_in[1];
  const int*   mask = (const int*)d_in[2];
  const float* Wq   = (const float*)d_in[3];
  const float* Wkv  = (const float*)d_in[4];
  const float* Wh   = (const float*)d_in[5];
  const float* bh   = (const float*)d_in[6];
  float* out = (float*)d_out;
  (void)in_sizes; (void)n_in; (void)ws_size; (void)out_size;

  _Float16* wpack = (_Float16*)d_ws;   // 65536 halfs = 128 KB
  pack_weights<<<256, 256, 0, stream>>>(Wkv, Wq, Wh, wpack);
  local_atten_kernel<<<NATOM, 256, 0, stream>>>(g1, gg1, mask, wpack, bh, out);
}

// Round 3
// 311.960 us; speedup vs baseline: 1.3689x; 1.3689x over previous
//
#include <hip/hip_runtime.h>
#include <hip/hip_fp16.h>
#include <math.h>

#define NATOM 8192  // NB * NLOC

namespace {

typedef _Float16 half8 __attribute__((ext_vector_type(8)));
typedef _Float16 half2t __attribute__((ext_vector_type(2)));
typedef float f32x4 __attribute__((ext_vector_type(4)));

// ws layout (halfs): [0,32768) wkvp | [32768,49152) Wqp_t | [49152,65536) Whp_t
// wkvp: 32 MFMA A-tiles of 16 kv-columns each.
//   Tiles 0..15  = K columns (orig Wkv col c = d*8 + h)
//   Tiles 16..31 = V columns (orig Wkv col c = d*8 + 4 + h)
//   Tile T, row m (0..15): d = (T&15)*4 + (m>>2), h = m&3
//   A-frag element: lane l = lqk*16 + m holds features i = ks*32 + lqk*8 + jj
__global__ void pack_weights(const float* __restrict__ Wkv,
                             const float* __restrict__ Wq,
                             const float* __restrict__ Wh,
                             _Float16* __restrict__ out) {
  int tid = blockIdx.x * 256 + threadIdx.x;  // 0..65535
  if (tid < 32768) {
    // (i,c) with c fastest -> coalesced read of Wkv[i][c]
    int i = tid >> 9, c = tid & 511;
    int ks = i >> 5, jj = i & 7, lqk = (i >> 3) & 3;
    int d = c >> 3, e = c & 7, isv = e >> 2, h = e & 3;
    int T = isv * 16 + (d >> 2);
    int m = ((d & 3) << 2) | h;
    int l = lqk * 16 + m;
    out[(((T * 2 + ks) * 64) + l) * 8 + jj] = (_Float16)Wkv[i * 512 + c];
  } else if (tid < 49152) {
    int idx = tid - 32768;          // Wq is [i][c], 64x256
    int i = idx >> 8, c = idx & 255;
    out[32768 + c * 64 + i] = (_Float16)Wq[i * 256 + c];   // Wqp_t[c][i]
  } else {
    int idx = tid - 49152;          // Wh is [k][c], 256x64
    int k = idx >> 6, c = idx & 63;
    out[49152 + c * 256 + k] = (_Float16)Wh[k * 64 + c];   // Whp_t[c][k]
  }
}

__device__ __forceinline__ float dot8(half8 a, half8 b, float acc) {
  acc = __builtin_amdgcn_fdot2((half2t){a[0], a[1]}, (half2t){b[0], b[1]}, acc, false);
  acc = __builtin_amdgcn_fdot2((half2t){a[2], a[3]}, (half2t){b[2], b[3]}, acc, false);
  acc = __builtin_amdgcn_fdot2((half2t){a[4], a[5]}, (half2t){b[4], b[5]}, acc, false);
  acc = __builtin_amdgcn_fdot2((half2t){a[6], a[7]}, (half2t){b[6], b[7]}, acc, false);
  return acc;
}

// launch_bounds(256, 6): VGPR cap = 512/6 ~= 84 — fits the live set (sacc[16] +
// a-frags[8] + b-frags[8] + q4[4] + addressing) with NO scratch spills.
// (256, 8) capped at 64 and the compiler spilled: WRITE_SIZE blew up to 345 MB
// (42 KB/block of spill-fill) and dur doubled. 6 blocks/CU = 24 waves = 75% occ,
// still 1.8x the original 4-block config. LDS 12.4 KB permits 12 blocks; VGPR
// is the binding limit by design.
__global__ __launch_bounds__(256, 6)
void local_atten_kernel(const float* __restrict__ g1,
                        const float* __restrict__ gg1,
                        const int* __restrict__ mask,
                        const _Float16* __restrict__ wpack,
                        const float* __restrict__ bh,
                        float* __restrict__ out) {
  // LDS: 8192 + 128 + 3072 + 512 + 512 = 12416 B
  __shared__ __align__(16) __half gs[64 * 64];          // gg1 tile, fp16, swizzled
  __shared__ __align__(16) __half g1h[64];
  __shared__ __align__(16) unsigned char blob[3072];    // qs+sred ; later redbuf
  __shared__ __align__(8) __half aws2[64][4];           // softmax weights [j][h]
  __shared__ __align__(16) __half rets[256];            // o flat k = h*64 + d

  float* qs = reinterpret_cast<float*>(blob);                    // [256] fp32
  __half (*sred)[4][64] = reinterpret_cast<__half(*)[4][64]>(blob + 1024);  // [w][h][j]
  float (*redbuf)[64] = reinterpret_cast<float(*)[64]>(blob);    // [w][c] (aliases qs)

  const _Float16* wkvp = wpack;
  const _Float16* wqp  = wpack + 32768;
  const _Float16* whp  = wpack + 49152;

  const int t = threadIdx.x;
  const int lane = t & 63;
  const int wave = t >> 6;
  const int lq = lane >> 4;   // quad within wave
  const int lr = lane & 15;
  const int atom = blockIdx.x;

  // ---- hoisted small loads: latency hidden behind staging + first barrier ----
  const int mreg = mask[(size_t)atom * 64 + lane];
  const float bhv = bh[lane];
  if (t < 64) g1h[t] = __float2half(g1[(size_t)atom * 64 + t]);

  // ---- stage gg1 tile (64 nei x 64 feat) as fp16, swizzled for B-frag b128 ----
  // logical gs[j][i]; physical half offset = j*64 + ((g ^ (j&7))<<3) + (i&7), g=i>>3
  {
    const float4* src = reinterpret_cast<const float4*>(gg1 + (size_t)atom * 4096);
#pragma unroll
    for (int r = 0; r < 4; ++r) {
      int idx4 = t + 256 * r;          // 0..1023 float4s
      int j = idx4 >> 4;               // neighbor row
      int i4 = (idx4 & 15) << 2;       // feature start (multiple of 4)
      float4 v = src[idx4];
      __half2 h01 = __floats2half2_rn(v.x, v.y);
      __half2 h23 = __floats2half2_rn(v.z, v.w);
      int g = i4 >> 3;
      int addr = j * 64 + ((g ^ (j & 7)) << 3) + (i4 & 7);
      union { __half2 h[2]; uint2 u; } pk;
      pk.h[0] = h01; pk.h[1] = h23;
      *reinterpret_cast<uint2*>(&gs[addr]) = pk.u;
    }
  }

  // B-fragment lane pointers: j = jt*16+lr, k-chunk g = ks*4+lq.
  // Swizzle term depends only on (lr,lq,ks): addr = jt*1024 + lr*64 + ((g^(lr&7))<<3)
  // -> two base pointers + jt*2048B immediate offsets; gs stays live all kernel
  // (no vbuf overwrite), so fragments are re-read per phase instead of pinned
  // in 32 VGPRs. ds_read_b128, uniform 8 accesses/bank (conflict-free).
  const __half* bp0 = &gs[lr * 64 + ((lq ^ (lr & 7)) << 3)];
  const __half* bp1 = &gs[lr * 64 + (((4 + lq) ^ (lr & 7)) << 3)];

  // ---- q = g1row @ Wq (fp16 dot2): thread t owns flat column t (= d*4 + h) ----
  __syncthreads();
  {
    float qacc = 0.f;
    const half8* wrow = reinterpret_cast<const half8*>(wqp + t * 64);
    const half8* grow = reinterpret_cast<const half8*>(&g1h[0]);
#pragma unroll
    for (int ks = 0; ks < 8; ++ks) qacc = dot8(wrow[ks], grow[ks], qacc);
    qs[t] = qacc;
  }
  __syncthreads();

  const half8* ap_base = reinterpret_cast<const half8*>(wkvp);

  // ---- phase 1: K-tiles only (T = wave*4 + it). Lane holds K[d=T*4+lq][h=r][j].
  // Score partial s[h][j] accumulates q[d][h]*K immediately; fold over lq after.
  float sacc[4][4];  // [jt][h]
#pragma unroll
  for (int jt = 0; jt < 4; ++jt)
#pragma unroll
    for (int h = 0; h < 4; ++h) sacc[jt][h] = 0.f;

#pragma unroll
  for (int it = 0; it < 4; ++it) {
    const int T = wave * 4 + it;
    half8 a0 = ap_base[T * 128 + lane];
    half8 a1 = ap_base[T * 128 + 64 + lane];
    const int d = T * 4 + lq;
    float4 q4 = *reinterpret_cast<const float4*>(&qs[d * 4]);  // q[d][0..3]
#pragma unroll
    for (int jt = 0; jt < 4; ++jt) {
      half8 b0 = *reinterpret_cast<const half8*>(bp0 + jt * 1024);
      half8 b1 = *reinterpret_cast<const half8*>(bp1 + jt * 1024);
      f32x4 acc = {0.f, 0.f, 0.f, 0.f};
      acc = __builtin_amdgcn_mfma_f32_16x16x32_f16(a0, b0, acc, 0, 0, 0);
      acc = __builtin_amdgcn_mfma_f32_16x16x32_f16(a1, b1, acc, 0, 0, 0);
      sacc[jt][0] = fmaf(acc[0], q4.x, sacc[jt][0]);
      sacc[jt][1] = fmaf(acc[1], q4.y, sacc[jt][1]);
      sacc[jt][2] = fmaf(acc[2], q4.z, sacc[jt][2]);
      sacc[jt][3] = fmaf(acc[3], q4.w, sacc[jt][3]);
    }
  }

  // fold score partials over all 4 quads (d-sum), publish per-wave partials
#pragma unroll
  for (int jt = 0; jt < 4; ++jt)
#pragma unroll
    for (int h = 0; h < 4; ++h) {
      sacc[jt][h] += __shfl_xor(sacc[jt][h], 16);
      sacc[jt][h] += __shfl_xor(sacc[jt][h], 32);
    }
  if (lq == 0) {
#pragma unroll
    for (int h = 0; h < 4; ++h)
#pragma unroll
      for (int jt = 0; jt < 4; ++jt)
        sred[wave][h][jt * 16 + lr] = __float2half(sacc[jt][h]);
  }
  __syncthreads();

  // ---- masked softmax over j (wave-wide): h = wave, j = lane ----
  {
    float s = __half2float(sred[0][wave][lane]) + __half2float(sred[1][wave][lane]) +
              __half2float(sred[2][wave][lane]) + __half2float(sred[3][wave][lane]);
    s *= 0.125f;                                          // 1/sqrt(64)
    s = mreg ? s : -INFINITY;
    float mx = s;
#pragma unroll
    for (int off = 32; off > 0; off >>= 1) mx = fmaxf(mx, __shfl_xor(mx, off));
    float pe = mreg ? __expf(s - mx) : 0.f;
    float sum = pe;
#pragma unroll
    for (int off = 32; off > 0; off >>= 1) sum += __shfl_xor(sum, off);
    float aw = (sum > 0.f) ? (pe / sum) : 0.f;
    aws2[lane][wave] = __float2half(aw);                  // [j][h]
  }
  __syncthreads();

  // ---- attnw for this lane's j-columns, as floats: awf[jt][h] = aw[h][jt*16+lr] ----
  float awf[4][4];
#pragma unroll
  for (int jt = 0; jt < 4; ++jt) {
    union { uint2 u; __half2 h[2]; } awu;
    awu.u = *reinterpret_cast<const uint2*>(&aws2[jt * 16 + lr][0]);  // b64 broadcast
    float2 f01 = __half22float2(awu.h[0]);
    float2 f23 = __half22float2(awu.h[1]);
    awf[jt][0] = f01.x; awf[jt][1] = f01.y; awf[jt][2] = f23.x; awf[jt][3] = f23.y;
  }

  // ---- phase 2: V-tiles (T = 16 + wave*4 + it). Lane holds V[d'=...][h=r][j];
  // PV contraction straight out of the accumulators: part[r] = sum_j aw[r][j]*V,
  // j-sum completed by a 16-lane butterfly. v never touches LDS.
#pragma unroll
  for (int it = 0; it < 4; ++it) {
    const int T = 16 + wave * 4 + it;
    half8 a0 = ap_base[T * 128 + lane];
    half8 a1 = ap_base[T * 128 + 64 + lane];
    float part[4] = {0.f, 0.f, 0.f, 0.f};
#pragma unroll
    for (int jt = 0; jt < 4; ++jt) {
      half8 b0 = *reinterpret_cast<const half8*>(bp0 + jt * 1024);
      half8 b1 = *reinterpret_cast<const half8*>(bp1 + jt * 1024);
      f32x4 acc = {0.f, 0.f, 0.f, 0.f};
      acc = __builtin_amdgcn_mfma_f32_16x16x32_f16(a0, b0, acc, 0, 0, 0);
      acc = __builtin_amdgcn_mfma_f32_16x16x32_f16(a1, b1, acc, 0, 0, 0);
      part[0] = fmaf(acc[0], awf[jt][0], part[0]);
      part[1] = fmaf(acc[1], awf[jt][1], part[1]);
      part[2] = fmaf(acc[2], awf[jt][2], part[2]);
      part[3] = fmaf(acc[3], awf[jt][3], part[3]);
    }
#pragma unroll
    for (int r = 0; r < 4; ++r) {
      part[r] += __shfl_xor(part[r], 1);
      part[r] += __shfl_xor(part[r], 2);
      part[r] += __shfl_xor(part[r], 4);
      part[r] += __shfl_xor(part[r], 8);
    }
    if (lr == 0) {
      const int d = (T - 16) * 4 + lq;      // covers 0..63 across waves*its*quads
#pragma unroll
      for (int r = 0; r < 4; ++r) rets[r * 64 + d] = __float2half(part[r]);
    }
  }
  __syncthreads();   // rets is cross-wave

  // ---- out = ret @ Wh + bh (fp16 dot2): c = lane, k-range = wave*64.. ----
  // Wh read straight from L2-hot wpack; 24-wave TLP hides the latency.
  {
    float part = 0.f;
    const half8* wrow = reinterpret_cast<const half8*>(whp + lane * 256 + wave * 64);
    const half8* rrow = reinterpret_cast<const half8*>(&rets[wave * 64]);  // broadcast
#pragma unroll
    for (int ks = 0; ks < 8; ++ks) part = dot8(wrow[ks], rrow[ks], part);
    redbuf[wave][lane] = part;
  }
  __syncthreads();
  if (t < 64)
    out[(size_t)atom * 64 + t] =
        redbuf[0][t] + redbuf[1][t] + redbuf[2][t] + redbuf[3][t] + bhv;
}

}  // namespace

extern "C" void kernel_launch(void* const* d_in, const int* in_sizes, int n_in,
                              void* d_out, int out_size, void* d_ws, size_t ws_size,
                              hipStream_t stream) {
  const float* g1   = (const float*)d_in[0];
  const float* gg1  = (const float*)d_in[1];
  const int*   mask = (const int*)d_in[2];
  const float* Wq   = (const float*)d_in[3];
  const float* Wkv  = (const float*)d_in[4];
  const float* Wh   = (const float*)d_in[5];
  const float* bh   = (const float*)d_in[6];
  float* out = (float*)d_out;
  (void)in_sizes; (void)n_in; (void)ws_size; (void)out_size;

  _Float16* wpack = (_Float16*)d_ws;   // 65536 halfs = 128 KB
  pack_weights<<<256, 256, 0, stream>>>(Wkv, Wq, Wh, wpack);
  local_atten_kernel<<<NATOM, 256, 0, stream>>>(g1, gg1, mask, wpack, bh, out);
}

// Round 4
// 280.331 us; speedup vs baseline: 1.5233x; 1.1128x over previous
//
#include <hip/hip_runtime.h>
#include <hip/hip_fp16.h>
#include <math.h>

#define NATOM 8192  // NB * NLOC

namespace {

typedef _Float16 half8 __attribute__((ext_vector_type(8)));
typedef _Float16 half2t __attribute__((ext_vector_type(2)));
typedef float f32x4 __attribute__((ext_vector_type(4)));

// ws layout (halfs): [0,32768) wkvp | [32768,49152) Wqp_t | [49152,65536) Whp_t
// wkvp: 32 MFMA A-tiles of 16 kv-columns each.
//   Tiles 0..15  = K columns (orig Wkv col c = d*8 + h)
//   Tiles 16..31 = V columns (orig Wkv col c = d*8 + 4 + h)
//   Tile T, row m (0..15): d = (T&15)*4 + (m>>2), h = m&3
//   A-frag element: lane l = lqk*16 + m holds features i = ks*32 + lqk*8 + jj
__global__ void pack_weights(const float* __restrict__ Wkv,
                             const float* __restrict__ Wq,
                             const float* __restrict__ Wh,
                             _Float16* __restrict__ out) {
  int tid = blockIdx.x * 256 + threadIdx.x;  // 0..65535
  if (tid < 32768) {
    // (i,c) with c fastest -> coalesced read of Wkv[i][c]
    int i = tid >> 9, c = tid & 511;
    int ks = i >> 5, jj = i & 7, lqk = (i >> 3) & 3;
    int d = c >> 3, e = c & 7, isv = e >> 2, h = e & 3;
    int T = isv * 16 + (d >> 2);
    int m = ((d & 3) << 2) | h;
    int l = lqk * 16 + m;
    out[(((T * 2 + ks) * 64) + l) * 8 + jj] = (_Float16)Wkv[i * 512 + c];
  } else if (tid < 49152) {
    int idx = tid - 32768;          // Wq is [i][c], 64x256
    int i = idx >> 8, c = idx & 255;
    out[32768 + c * 64 + i] = (_Float16)Wq[i * 256 + c];   // Wqp_t[c][i]
  } else {
    int idx = tid - 49152;          // Wh is [k][c], 256x64
    int k = idx >> 6, c = idx & 63;
    out[49152 + c * 256 + k] = (_Float16)Wh[k * 64 + c];   // Whp_t[c][k]
  }
}

__device__ __forceinline__ float dot8(half8 a, half8 b, float acc) {
  acc = __builtin_amdgcn_fdot2((half2t){a[0], a[1]}, (half2t){b[0], b[1]}, acc, false);
  acc = __builtin_amdgcn_fdot2((half2t){a[2], a[3]}, (half2t){b[2], b[3]}, acc, false);
  acc = __builtin_amdgcn_fdot2((half2t){a[4], a[5]}, (half2t){b[4], b[5]}, acc, false);
  acc = __builtin_amdgcn_fdot2((half2t){a[6], a[7]}, (half2t){b[6], b[7]}, acc, false);
  return acc;
}

// launch_bounds(256, 4): VGPR budget 128. Forcing 6 or 8 waves/EU (rounds 2-3)
// made the compiler spill to scratch (WRITE_SIZE 345/26 MB) and regressed.
// Round-0 evidence: with budget 128 the allocator is frugal (64 VGPR there).
// LDS is 12.4 KB, so occupancy is VGPR-bound at ~5-6 waves/SIMD — still well
// above the 37.9 KB/4-block original.
__global__ __launch_bounds__(256, 4)
void local_atten_kernel(const float* __restrict__ g1,
                        const float* __restrict__ gg1,
                        const int* __restrict__ mask,
                        const _Float16* __restrict__ wpack,
                        const float* __restrict__ bh,
                        float* __restrict__ out) {
  // LDS: 8192 + 128 + 3072 + 512 + 512 = 12416 B
  __shared__ __align__(16) __half gs[64 * 64];          // gg1 tile, fp16, swizzled
  __shared__ __align__(16) __half g1h[64];
  __shared__ __align__(16) unsigned char blob[3072];    // qs+sred ; later redbuf
  __shared__ __align__(8) __half aws2[64][4];           // softmax weights [j][h]
  __shared__ __align__(16) __half rets[256];            // o flat k = h*64 + d

  float* qs = reinterpret_cast<float*>(blob);                    // [256] fp32
  __half (*sred)[4][64] = reinterpret_cast<__half(*)[4][64]>(blob + 1024);  // [w][h][j]
  float (*redbuf)[64] = reinterpret_cast<float(*)[64]>(blob);    // [w][c] (aliases qs)

  const _Float16* wkvp = wpack;
  const _Float16* wqp  = wpack + 32768;
  const _Float16* whp  = wpack + 49152;

  const int t = threadIdx.x;
  const int lane = t & 63;
  const int wave = t >> 6;
  const int lq = lane >> 4;   // quad within wave
  const int lr = lane & 15;
  const int atom = blockIdx.x;

  if (t < 64) g1h[t] = __float2half(g1[(size_t)atom * 64 + t]);

  // ---- stage gg1 tile (64 nei x 64 feat) as fp16, swizzled for B-frag b128 ----
  // logical gs[j][i]; physical half offset = j*64 + ((g ^ (j&7))<<3) + (i&7), g=i>>3
  {
    const float4* src = reinterpret_cast<const float4*>(gg1 + (size_t)atom * 4096);
#pragma unroll
    for (int r = 0; r < 4; ++r) {
      int idx4 = t + 256 * r;          // 0..1023 float4s
      int j = idx4 >> 4;               // neighbor row
      int i4 = (idx4 & 15) << 2;       // feature start (multiple of 4)
      float4 v = src[idx4];
      __half2 h01 = __floats2half2_rn(v.x, v.y);
      __half2 h23 = __floats2half2_rn(v.z, v.w);
      int g = i4 >> 3;
      int addr = j * 64 + ((g ^ (j & 7)) << 3) + (i4 & 7);
      union { __half2 h[2]; uint2 u; } pk;
      pk.h[0] = h01; pk.h[1] = h23;
      *reinterpret_cast<uint2*>(&gs[addr]) = pk.u;
    }
  }
  __syncthreads();

  // ---- B-fragments (gg1) pinned in regs: read ONCE (8 ds_read_b128/wave),
  // not per tile-iteration. j = jt*16+lr, k-chunk g = ks*4+lq; swizzle term is
  // jt-invariant so addresses fold to 2 lane pointers + jt*2048B immediates.
  half8 bfrag[4][2];
  {
    const __half* bp0 = &gs[lr * 64 + ((lq ^ (lr & 7)) << 3)];
    const __half* bp1 = &gs[lr * 64 + (((4 + lq) ^ (lr & 7)) << 3)];
#pragma unroll
    for (int jt = 0; jt < 4; ++jt) {
      bfrag[jt][0] = *reinterpret_cast<const half8*>(bp0 + jt * 1024);
      bfrag[jt][1] = *reinterpret_cast<const half8*>(bp1 + jt * 1024);
    }
  }

  // ---- prefetch first K-tile A-fragments (hidden behind q GEMM) ----
  const half8* ap_base = reinterpret_cast<const half8*>(wkvp);
  half8 a0 = ap_base[(wave * 4) * 128 + lane];
  half8 a1 = ap_base[(wave * 4) * 128 + 64 + lane];

  // ---- q = g1row @ Wq (fp16 dot2): thread t owns flat column t (= d*4 + h) ----
  {
    float qacc = 0.f;
    const half8* wrow = reinterpret_cast<const half8*>(wqp + t * 64);
    const half8* grow = reinterpret_cast<const half8*>(&g1h[0]);
#pragma unroll
    for (int ks = 0; ks < 8; ++ks) qacc = dot8(wrow[ks], grow[ks], qacc);
    qs[t] = qacc;
  }
  __syncthreads();

  // ---- phase 1: K-tiles only (T = wave*4 + it). Lane holds K[d=T*4+lq][h=r][j].
  // Score partial s[h][j] accumulates q[d][h]*K immediately; fold over lq after.
  float sacc[4][4];  // [jt][h]
#pragma unroll
  for (int jt = 0; jt < 4; ++jt)
#pragma unroll
    for (int h = 0; h < 4; ++h) sacc[jt][h] = 0.f;

#pragma unroll
  for (int it = 0; it < 4; ++it) {
    const int T = wave * 4 + it;
    // depth-1 prefetch; last iteration prefetches this wave's first V-tile,
    // whose latency is then hidden under the fold + softmax + barriers.
    const int Tn = (it < 3) ? (T + 1) : (16 + wave * 4);
    half8 na0 = ap_base[Tn * 128 + lane];
    half8 na1 = ap_base[Tn * 128 + 64 + lane];

    const int d = T * 4 + lq;
    float4 q4 = *reinterpret_cast<const float4*>(&qs[d * 4]);  // q[d][0..3]
#pragma unroll
    for (int jt = 0; jt < 4; ++jt) {
      f32x4 acc = {0.f, 0.f, 0.f, 0.f};
      acc = __builtin_amdgcn_mfma_f32_16x16x32_f16(a0, bfrag[jt][0], acc, 0, 0, 0);
      acc = __builtin_amdgcn_mfma_f32_16x16x32_f16(a1, bfrag[jt][1], acc, 0, 0, 0);
      sacc[jt][0] = fmaf(acc[0], q4.x, sacc[jt][0]);
      sacc[jt][1] = fmaf(acc[1], q4.y, sacc[jt][1]);
      sacc[jt][2] = fmaf(acc[2], q4.z, sacc[jt][2]);
      sacc[jt][3] = fmaf(acc[3], q4.w, sacc[jt][3]);
    }
    a0 = na0; a1 = na1;
  }

  // mask loaded late (short live range); L3-resident, covered by the fold below
  const int mreg = mask[(size_t)atom * 64 + lane];

  // fold score partials over all 4 quads (d-sum), publish per-wave partials
#pragma unroll
  for (int jt = 0; jt < 4; ++jt)
#pragma unroll
    for (int h = 0; h < 4; ++h) {
      sacc[jt][h] += __shfl_xor(sacc[jt][h], 16);
      sacc[jt][h] += __shfl_xor(sacc[jt][h], 32);
    }
  if (lq == 0) {
#pragma unroll
    for (int h = 0; h < 4; ++h)
#pragma unroll
      for (int jt = 0; jt < 4; ++jt)
        sred[wave][h][jt * 16 + lr] = __float2half(sacc[jt][h]);
  }
  __syncthreads();

  // ---- masked softmax over j (wave-wide): h = wave, j = lane ----
  {
    float s = __half2float(sred[0][wave][lane]) + __half2float(sred[1][wave][lane]) +
              __half2float(sred[2][wave][lane]) + __half2float(sred[3][wave][lane]);
    s *= 0.125f;                                          // 1/sqrt(64)
    s = mreg ? s : -INFINITY;
    float mx = s;
#pragma unroll
    for (int off = 32; off > 0; off >>= 1) mx = fmaxf(mx, __shfl_xor(mx, off));
    float pe = mreg ? __expf(s - mx) : 0.f;
    float sum = pe;
#pragma unroll
    for (int off = 32; off > 0; off >>= 1) sum += __shfl_xor(sum, off);
    float aw = (sum > 0.f) ? (pe / sum) : 0.f;
    aws2[lane][wave] = __float2half(aw);                  // [j][h]
  }
  __syncthreads();

  // ---- attnw for this lane's j-columns, as floats: awf[jt][h] = aw[h][jt*16+lr] ----
  float awf[4][4];
#pragma unroll
  for (int jt = 0; jt < 4; ++jt) {
    union { uint2 u; __half2 h[2]; } awu;
    awu.u = *reinterpret_cast<const uint2*>(&aws2[jt * 16 + lr][0]);  // b64 broadcast
    float2 f01 = __half22float2(awu.h[0]);
    float2 f23 = __half22float2(awu.h[1]);
    awf[jt][0] = f01.x; awf[jt][1] = f01.y; awf[jt][2] = f23.x; awf[jt][3] = f23.y;
  }

  // ---- phase 2: V-tiles (T = 16 + wave*4 + it). Lane holds V[d][h=r][j];
  // PV contraction straight out of the accumulators: part[r] = sum_j aw[r][j]*V,
  // j-sum completed by a 16-lane butterfly. v never touches LDS.
#pragma unroll
  for (int it = 0; it < 4; ++it) {
    const int T = 16 + wave * 4 + it;
    half8 na0 = a0, na1 = a1;
    if (it < 3) {
      na0 = ap_base[(T + 1) * 128 + lane];
      na1 = ap_base[(T + 1) * 128 + 64 + lane];
    }
    float part[4] = {0.f, 0.f, 0.f, 0.f};
#pragma unroll
    for (int jt = 0; jt < 4; ++jt) {
      f32x4 acc = {0.f, 0.f, 0.f, 0.f};
      acc = __builtin_amdgcn_mfma_f32_16x16x32_f16(a0, bfrag[jt][0], acc, 0, 0, 0);
      acc = __builtin_amdgcn_mfma_f32_16x16x32_f16(a1, bfrag[jt][1], acc, 0, 0, 0);
      part[0] = fmaf(acc[0], awf[jt][0], part[0]);
      part[1] = fmaf(acc[1], awf[jt][1], part[1]);
      part[2] = fmaf(acc[2], awf[jt][2], part[2]);
      part[3] = fmaf(acc[3], awf[jt][3], part[3]);
    }
#pragma unroll
    for (int r = 0; r < 4; ++r) {
      part[r] += __shfl_xor(part[r], 1);
      part[r] += __shfl_xor(part[r], 2);
      part[r] += __shfl_xor(part[r], 4);
      part[r] += __shfl_xor(part[r], 8);
    }
    if (lr == 0) {
      const int d = (T - 16) * 4 + lq;      // covers 0..63 across waves*its*quads
#pragma unroll
      for (int r = 0; r < 4; ++r) rets[r * 64 + d] = __float2half(part[r]);
    }
    a0 = na0; a1 = na1;
  }
  __syncthreads();   // rets is cross-wave

  // ---- out = ret @ Wh + bh (fp16 dot2): c = lane, k-range = wave*64.. ----
  // Wh read straight from L2-hot wpack; TLP hides the latency.
  {
    float part = 0.f;
    const half8* wrow = reinterpret_cast<const half8*>(whp + lane * 256 + wave * 64);
    const half8* rrow = reinterpret_cast<const half8*>(&rets[wave * 64]);  // broadcast
#pragma unroll
    for (int ks = 0; ks < 8; ++ks) part = dot8(wrow[ks], rrow[ks], part);
    redbuf[wave][lane] = part;
  }
  __syncthreads();
  if (t < 64)
    out[(size_t)atom * 64 + t] =
        redbuf[0][t] + redbuf[1][t] + redbuf[2][t] + redbuf[3][t] + bh[t];
}

}  // namespace

extern "C" void kernel_launch(void* const* d_in, const int* in_sizes, int n_in,
                              void* d_out, int out_size, void* d_ws, size_t ws_size,
                              hipStream_t stream) {
  const float* g1   = (const float*)d_in[0];
  const float* gg1  = (const float*)d_in[1];
  const int*   mask = (const int*)d_in[2];
  const float* Wq   = (const float*)d_in[3];
  const float* Wkv  = (const float*)d_in[4];
  const float* Wh   = (const float*)d_in[5];
  const float* bh   = (const float*)d_in[6];
  float* out = (float*)d_out;
  (void)in_sizes; (void)n_in; (void)ws_size; (void)out_size;

  _Float16* wpack = (_Float16*)d_ws;   // 65536 halfs = 128 KB
  pack_weights<<<256, 256, 0, stream>>>(Wkv, Wq, Wh, wpack);
  local_atten_kernel<<<NATOM, 256, 0, stream>>>(g1, gg1, mask, wpack, bh, out);
}